// Round 1
// 399.002 us; speedup vs baseline: 1.0168x; 1.0168x over previous
//
#include <hip/hip_runtime.h>
#include <stdint.h>

#define IN_F   2048
#define OUT_F  2048
#define NROWS  8192   // 4 * 2048
#define BK     64
#define BM     256    // block M tile
#define BN     128    // block N tile

typedef __bf16 bf16x8 __attribute__((ext_vector_type(8)));
typedef float  f32x16 __attribute__((ext_vector_type(16)));
typedef unsigned short ushort8v __attribute__((ext_vector_type(8)));

// ---------- helpers ----------

__device__ __forceinline__ unsigned short f2bf_rtne(float f) {
    unsigned int u = __float_as_uint(f);
    u += 0x7FFFu + ((u >> 16) & 1u);   // round-to-nearest-even on bf16 boundary
    return (unsigned short)(u >> 16);
}

__device__ __forceinline__ float softplusf(float v) {
    float a = fabsf(v);
    return fmaxf(v, 0.0f) + log1pf(__expf(-a));
}

// async global->LDS, 16B per lane; LDS dest is wave-uniform base + lane*16
__device__ __forceinline__ void gload_lds16(const void* g, void* l) {
    __builtin_amdgcn_global_load_lds(
        (const __attribute__((address_space(1))) unsigned int*)g,
        (__attribute__((address_space(3))) unsigned int*)l,
        16 /*bytes*/, 0 /*offset*/, 0 /*aux*/);
}

// ---------- prep: fused fp32 -> bf16 conversions into workspace ----------

__global__ __launch_bounds__(256)
void prep_kernel(const float* __restrict__ x, const float* __restrict__ mu,
                 const float* __restrict__ sg,
                 unsigned short* __restrict__ xb, unsigned short* __restrict__ kh,
                 unsigned short* __restrict__ mh) {
    const int b = blockIdx.x;
    const int t = threadIdx.x;
    if (b < 8192) {
        const size_t i = ((size_t)b * 256 + t) * 8;
        float4 v0 = *(const float4*)(x + i);
        float4 v1 = *(const float4*)(x + i + 4);
        ushort8v o;
        o[0] = f2bf_rtne(v0.x); o[1] = f2bf_rtne(v0.y);
        o[2] = f2bf_rtne(v0.z); o[3] = f2bf_rtne(v0.w);
        o[4] = f2bf_rtne(v1.x); o[5] = f2bf_rtne(v1.y);
        o[6] = f2bf_rtne(v1.z); o[7] = f2bf_rtne(v1.w);
        *(ushort8v*)(xb + i) = o;
    } else {
        const size_t i = ((size_t)(b - 8192) * 256 + t) * 8;
        float4 m0 = *(const float4*)(mu + i);
        float4 m1 = *(const float4*)(mu + i + 4);
        float4 s0 = *(const float4*)(sg + i);
        float4 s1 = *(const float4*)(sg + i + 4);
        ushort8v ko, mo;
        ko[0] = f2bf_rtne(m0.x * softplusf(s0.x));
        ko[1] = f2bf_rtne(m0.y * softplusf(s0.y));
        ko[2] = f2bf_rtne(m0.z * softplusf(s0.z));
        ko[3] = f2bf_rtne(m0.w * softplusf(s0.w));
        ko[4] = f2bf_rtne(m1.x * softplusf(s1.x));
        ko[5] = f2bf_rtne(m1.y * softplusf(s1.y));
        ko[6] = f2bf_rtne(m1.z * softplusf(s1.z));
        ko[7] = f2bf_rtne(m1.w * softplusf(s1.w));
        mo[0] = f2bf_rtne(m0.x); mo[1] = f2bf_rtne(m0.y);
        mo[2] = f2bf_rtne(m0.z); mo[3] = f2bf_rtne(m0.w);
        mo[4] = f2bf_rtne(m1.x); mo[5] = f2bf_rtne(m1.y);
        mo[6] = f2bf_rtne(m1.z); mo[7] = f2bf_rtne(m1.w);
        *(ushort8v*)(kh + i) = ko;
        *(ushort8v*)(mh + i) = mo;
    }
}

// ---------- fused double-GEMM, 2-phase pipelined ----------
// Block tile 256(M)x128(N), 8 waves (512 thr), wave grid 4Mx2N -> wave tile
// 64x64 per B-matrix, dual acc (scores/comp) sharing A-frags: per k-chunk
// 6 ds_read_b128 feed 8 MFMAs (42.7 FLOP/LDS-byte vs 32 before).
// LDS: 2 x (A 32KB | K 16KB | M 16KB) = 128 KB, 1 block/CU, 2 waves/SIMD.
// K-loop: STAGE(next tile, other buffer) -> COMPUTE(current) ->
// vmcnt(0)+lgkmcnt(0) -> raw s_barrier. Loads overlap the whole compute
// phase instead of a dead drain between two __syncthreads.
// LDS rows are 128B = 8 x 16B chunks, chunk XOR-swizzled by (row&7) on the
// DMA *source* side; read side applies the same involution.

__global__ __launch_bounds__(512, 2)
void gemm_fused_kernel(const unsigned short* __restrict__ xb,  // [8192][2048] bf16
                       const unsigned short* __restrict__ kh,  // [2048][2048] bf16 keys
                       const unsigned short* __restrict__ mh,  // [2048][2048] bf16 mu
                       const float* __restrict__ gate,         // [2048]
                       float* __restrict__ out0,               // masked  [8192][2048]
                       float* __restrict__ out1,               // scores  [8192][2048]
                       float* __restrict__ out2)               // masked  [8192][2048]
{
    __shared__ __align__(16) unsigned short lds[2][32768];  // 2 x 64 KB

    const int tid  = threadIdx.x;
    const int lane = tid & 63;
    const int wv   = tid >> 6;

    // XCD-aware bijective swizzle: 512 wgs, 8 XCDs, 64 consecutive wgs/XCD.
    // bo fastest -> each XCD works 4 bm-panels x all 16 bo-panels: K/M slices
    // for one K-step (16 x 32KB) stay hot in that XCD's 4MB L2.
    const int swz = (blockIdx.x & 7) * 64 + (blockIdx.x >> 3);
    const int bm  = swz >> 4;    // 0..31 over rows (M)
    const int bo  = swz & 15;    // 0..15 over output features (N)

    const int wm = (wv >> 1) * 64;   // wave M offset: 0,64,128,192
    const int wn = (wv & 1) * 64;    // wave N offset: 0,64

    // staging: region = 1KB = 8 rows x 128B; lane covers 16B chunk (lane&7)
    // of row (lane>>3); source chunk swizzled by row&7 (= srow).
    const int srow = lane >> 3;
    const int scol = ((lane & 7) ^ srow) * 8;

    // fragment coords: frag row = lane&31 within a 32-row subtile; k-chunk
    // selector uses hi = lane>>5.
    const int fm = lane & 31;
    const int hi = lane >> 5;
    const int sw = fm & 7;

    const unsigned short* xA = xb + (size_t)(bm * BM + wv * 32 + srow) * IN_F + scol;
    const unsigned short* xK = kh + (size_t)(bo * BN + wv * 16 + srow) * IN_F + scol;
    const unsigned short* xM = mh + (size_t)(bo * BN + wv * 16 + srow) * IN_F + scol;

    f32x16 accS[2][2], accC[2][2];
#pragma unroll
    for (int i = 0; i < 2; ++i)
#pragma unroll
        for (int j = 0; j < 2; ++j)
#pragma unroll
            for (int r = 0; r < 16; ++r) { accS[i][j][r] = 0.f; accC[i][j][r] = 0.f; }

    // A: 32 regions (4/wave); K,M: 16 regions (2/wave). 8 gloads/thread/K-tile.
    auto STAGE = [&](int kt, unsigned short* L) {
#pragma unroll
        for (int j = 0; j < 4; ++j)
            gload_lds16(xA + (size_t)j * (8 * IN_F) + kt, L + (wv * 4 + j) * 512);
#pragma unroll
        for (int j = 0; j < 2; ++j) {
            gload_lds16(xK + (size_t)j * (8 * IN_F) + kt, L + 16384 + (wv * 2 + j) * 512);
            gload_lds16(xM + (size_t)j * (8 * IN_F) + kt, L + 24576 + (wv * 2 + j) * 512);
        }
    };

    auto COMPUTE = [&](const unsigned short* L) {
        const unsigned short* LA = L;
        const unsigned short* LK = L + 16384;
        const unsigned short* LM = L + 24576;
#pragma unroll
        for (int kc = 0; kc < 4; ++kc) {
            const int ce = (((kc * 2 + hi) ^ sw) * 8);
            bf16x8 a0 = *(const bf16x8*)&LA[(wm +      fm) * BK + ce];
            bf16x8 a1 = *(const bf16x8*)&LA[(wm + 32 + fm) * BK + ce];
            bf16x8 k0 = *(const bf16x8*)&LK[(wn +      fm) * BK + ce];
            bf16x8 k1 = *(const bf16x8*)&LK[(wn + 32 + fm) * BK + ce];
            bf16x8 m0 = *(const bf16x8*)&LM[(wn +      fm) * BK + ce];
            bf16x8 m1 = *(const bf16x8*)&LM[(wn + 32 + fm) * BK + ce];
            accS[0][0] = __builtin_amdgcn_mfma_f32_32x32x16_bf16(a0, k0, accS[0][0], 0, 0, 0);
            accS[0][1] = __builtin_amdgcn_mfma_f32_32x32x16_bf16(a0, k1, accS[0][1], 0, 0, 0);
            accS[1][0] = __builtin_amdgcn_mfma_f32_32x32x16_bf16(a1, k0, accS[1][0], 0, 0, 0);
            accS[1][1] = __builtin_amdgcn_mfma_f32_32x32x16_bf16(a1, k1, accS[1][1], 0, 0, 0);
            accC[0][0] = __builtin_amdgcn_mfma_f32_32x32x16_bf16(a0, m0, accC[0][0], 0, 0, 0);
            accC[0][1] = __builtin_amdgcn_mfma_f32_32x32x16_bf16(a0, m1, accC[0][1], 0, 0, 0);
            accC[1][0] = __builtin_amdgcn_mfma_f32_32x32x16_bf16(a1, m0, accC[1][0], 0, 0, 0);
            accC[1][1] = __builtin_amdgcn_mfma_f32_32x32x16_bf16(a1, m1, accC[1][1], 0, 0, 0);
        }
    };

    unsigned short* Lc = &lds[0][0];
    unsigned short* Ln = &lds[1][0];

    // prologue: stage tile 0, drain, sync
    STAGE(0, Lc);
    asm volatile("s_waitcnt vmcnt(0)" ::: "memory");
    __builtin_amdgcn_s_barrier();
    __builtin_amdgcn_sched_barrier(0);

    // 2-phase main loop: loads for tile t+1 in flight across the whole
    // compute of tile t; single drain+barrier per K-tile.
    for (int kt = BK; kt < IN_F; kt += BK) {
        STAGE(kt, Ln);
        COMPUTE(Lc);
        asm volatile("s_waitcnt vmcnt(0) lgkmcnt(0)" ::: "memory");
        __builtin_amdgcn_s_barrier();
        __builtin_amdgcn_sched_barrier(0);
        unsigned short* t = Lc; Lc = Ln; Ln = t;
    }
    COMPUTE(Lc);   // last tile, no prefetch

    // epilogue: 32x32 C/D layout: col = lane&31, row = (reg&3)+8*(reg>>2)+4*hi
    const float inv_sqrt_d = 0.022097086912079608f;  // 1/sqrt(2048)
    const size_t row_base = (size_t)bm * BM + wm;
    const int    col_base = bo * BN + wn;
    const float g0 = gate[col_base +      fm];
    const float g1 = gate[col_base + 32 + fm];

#pragma unroll
    for (int i = 0; i < 2; ++i) {
#pragma unroll
        for (int j = 0; j < 2; ++j) {
            const float g   = j ? g1 : g0;
            const int   col = col_base + j * 32 + fm;
#pragma unroll
            for (int reg = 0; reg < 16; ++reg) {
                const int ro = (reg & 3) + 8 * (reg >> 2) + 4 * hi;
                const size_t row = row_base + i * 32 + ro;
                const size_t idx = row * OUT_F + col;
                const float s = accS[i][j][reg] * inv_sqrt_d;
                const float c = accC[i][j][reg];
                float w = s - g;
                w = w > 0.f ? w : 0.f;
                const float m = c * w;
                // nontemporal: outputs are write-once, keep operand panels in L2
                __builtin_nontemporal_store(m, &out0[idx]);
                __builtin_nontemporal_store(s, &out1[idx]);
                __builtin_nontemporal_store(m, &out2[idx]);
            }
        }
    }
}

// ---------- launch ----------

extern "C" void kernel_launch(void* const* d_in, const int* in_sizes, int n_in,
                              void* d_out, int out_size, void* d_ws, size_t ws_size,
                              hipStream_t stream) {
    const float* x    = (const float*)d_in[0];   // [4,2048,2048]
    const float* mu   = (const float*)d_in[1];   // [2048,2048]
    const float* sg   = (const float*)d_in[2];   // [2048,2048]
    const float* gate = (const float*)d_in[3];   // [2048]

    float* out0 = (float*)d_out;                         // final_output
    float* out1 = out0 + (size_t)NROWS * OUT_F;          // scores
    float* out2 = out1 + (size_t)NROWS * OUT_F;          // masked_output

    // workspace layout (bf16): xb 33.55MB | kh 8.39MB | mh 8.39MB  (50.3MB)
    unsigned short* xb = (unsigned short*)d_ws;
    unsigned short* kh = xb + (size_t)NROWS * IN_F;
    unsigned short* mh = kh + (size_t)OUT_F * IN_F;

    prep_kernel<<<8192 + 2048, 256, 0, stream>>>(x, mu, sg, xb, kh, mh);

    dim3 grid(NROWS / BM * (OUT_F / BN));  // 32 * 16 = 512 blocks
    gemm_fused_kernel<<<grid, 512, 0, stream>>>(xb, kh, mh, gate, out0, out1, out2);
}